// Round 9
// baseline (625.204 us; speedup 1.0000x reference)
//
#include <hip/hip_runtime.h>
#include <hip/hip_bf16.h>

// BMMGroupedGEMM: out[e,m,n] = sum_k x[e,m,k] * w[e,n,k], rows m >= m_sizes[e] zeroed.
// E=8, MAX_M=2048, K=2048, N=8192. fp32 in/out.
// Round 9: R6 schedule (best measured, 421 us) + W-conversion FUSED into B-staging:
// cvt_w pass (137 us of pure HBM traffic) deleted. B staged reg-path from fp32 W:
//   P0(t): stageA(t+1,kh1) | load bl0=B(t+1,kh0) f32 | ds_reads kh0 | BAR |
//          32 MFMA kh0 | writeB(t+1,kh1)<-bl1 | vmcnt(6) lgkm(0) | BAR
//   P1(t): stageA(t+2,kh0) | load bl1=B(t+2,kh1) f32 | ds_reads kh1 | BAR |
//          32 MFMA kh1 | writeB(t+1,kh0)<-bl0 | vmcnt(6) lgkm(0) | BAR
// Ledger: writeB's cvt makes the compiler vmcnt-wait the 1-phase-old B loads,
// which (source order: stageA before loadB) also drains the A gloads staged 1-2
// phases back -- exactly the groups the next phase reads. Steady outstanding at
// each phase end = this phase's 2 A-gloads + 4 B-loads = vmcnt(6). ds_writes
// drained by lgkmcnt(0) before the closing barrier (raw s_barrier doesn't).
// Write-after-read gaps: every staged/written region's last reader is >=2
// barriers before the write lands. X stays bf16-prepassed (read 8x, amplified).

#define NE   8
#define MAXM 2048
#define KD   2048
#define ND   8192

#define BM   256
#define BN   256
#define BK   64
#define NTS  (KD/BK)     // 32 K-tiles per output tile

typedef __attribute__((ext_vector_type(8))) short          short8;
typedef __attribute__((ext_vector_type(8))) unsigned short us8;
typedef __attribute__((ext_vector_type(4))) float          f32x4;
typedef __attribute__((ext_vector_type(4))) unsigned short us4;

__device__ __forceinline__ unsigned short f2bf(float f) {
    union { float f; unsigned u; } v; v.f = f;
    unsigned u = v.u;
    return (unsigned short)((u + 0x7FFFu + ((u >> 16) & 1u)) >> 16);  // RNE
}

__device__ __forceinline__ void gload16(const void* g, void* l) {
    __builtin_amdgcn_global_load_lds(
        (const __attribute__((address_space(1))) void*)g,
        (__attribute__((address_space(3))) void*)l, 16, 0, 0);
}

// ---------------- Pass 1: fp32 -> bf16 for X, masked rows skipped ----------------
// (X is read up to 8x by the GEMM -- one per XCD -- so halving its bytes pays.
//  W is read once per staging, so it is converted on the fly inside the GEMM.)
__global__ __launch_bounds__(256) void cvt_x_kernel(const float* __restrict__ src,
                                                    unsigned short* __restrict__ dst,
                                                    const int* __restrict__ ms) {
    int bid = blockIdx.x;            // E*MAXM rows
    int e = bid >> 11, m = bid & 2047;
    if (m >= ms[e]) return;
    const float* s = src + ((size_t)e * MAXM + m) * KD;
    unsigned short* d = dst + ((size_t)e * MAXM + m) * KD;
    int t = threadIdx.x;
    const f32x4* s4 = (const f32x4*)(s + t * 8);
    f32x4 a = s4[0], b = s4[1];
    us8 v = (us8){f2bf(a[0]), f2bf(a[1]), f2bf(a[2]), f2bf(a[3]),
                  f2bf(b[0]), f2bf(b[1]), f2bf(b[2]), f2bf(b[3])};
    *(us8*)(d + t * 8) = v;
}

// ---------------- Pass 2: persistent 2-phase/K-tile 256x256 bf16 GEMM ----------------
// LDS: A[buf][kh] 256x32 bf16 (16KB) x4 = 64KB; B same = 64KB. Total 128KB.
// A: gload_lds, pre-swizzled GLOBAL source (involution ss). B: reg-staged from
// fp32 W, swizzle applied at the ds_write DEST (same involution). Read side for
// both: slot = kg ^ ((row>>1)&3). Measured conflict-free (rounds 3-8).
__global__ __launch_bounds__(512, 2) void ggemm_pers(
    const unsigned short* __restrict__ xb,  // [E][MAXM][KD] bf16 (d_ws)
    const float*          __restrict__ w,   // [E][ND][KD]  fp32 (original input)
    const int*   __restrict__ ms,
    float*       __restrict__ out)          // [E][MAXM][ND] fp32
{
    int p   = blockIdx.x;          // 256 blocks, 1 per CU
    int xcd = p & 7;
    int jj  = p >> 3;              // 0..31 within XCD
    int tid = threadIdx.x;

    __shared__ int s_live[8], s_dead[8], s_cnt[2];
    __shared__ unsigned short Ak[2][2][BM * 32];   // 64 KB
    __shared__ unsigned short Bk[2][2][BN * 32];   // 64 KB

    // Per-XCD work list, expert-major (balanced + supertile locality).
    if (tid == 0) {
        int nl = 0, nd = 0, cumL = 0, cumD = 0, il = jj, id = jj;
        #pragma unroll
        for (int e = 0; e < NE; ++e) {
            int L = (ms[e] + 255) >> 8;            // live br rows, 0..8
            int cntL = L << 2, cntD = (8 - L) << 2;
            while (il < cumL + cntL) { int o = il - cumL; s_live[nl++] = (e << 5) | ((o >> 2) << 2) | (o & 3); il += 32; }
            while (id < cumD + cntD) { int o = id - cumD; s_dead[nd++] = (e << 5) | ((L + (o >> 2)) << 2) | (o & 3); id += 32; }
            cumL += cntL; cumD += cntD;
        }
        s_cnt[0] = nl; s_cnt[1] = nd;
    }
    __syncthreads();

    // zero-fill dead tiles
    int ndead = s_cnt[1];
    #pragma unroll 1
    for (int d = 0; d < ndead; ++d) {
        int v = s_dead[d]; int e = v >> 5, br = (v >> 2) & 7, bcl = v & 3;
        float* outE = out + (size_t)e * MAXM * ND;
        int row0 = br * BM, col0 = (xcd * 4 + bcl) * BN;
        f32x4 z = (f32x4){0.f, 0.f, 0.f, 0.f};
        #pragma unroll
        for (int q = 0; q < 32; ++q) {
            int i2 = tid + q * 512;
            int rr = i2 >> 6, cc = (i2 & 63) << 2;
            *(f32x4*)(outE + (size_t)(row0 + rr) * ND + col0 + cc) = z;
        }
    }
    int nlive = s_cnt[0];
    if (nlive == 0) return;

    int wid = tid >> 6, lane = tid & 63;
    int wr = wid >> 2, wc = wid & 3;            // 2x4 wave grid; wave owns 128x64
    int lr = lane & 15, kg = lane >> 4;
    int srow  = lane >> 2;                      // row within 16-row 1KB block
    int ss    = (lane & 3) ^ ((lane >> 3) & 3); // involution (A source pre-swizzle)
    int sslot = lane & 3;                       // B: linear 16B slot
    int ssw   = sslot ^ ((lane >> 3) & 3);      // B: swizzled dest slot (== ss)

    auto stageA = [&](int b, int kh, const unsigned short* xP, int kt) {
        #pragma unroll
        for (int q = 0; q < 2; ++q) {
            int blk = wid * 2 + q;
            const unsigned short* src =
                xP + (size_t)(blk * 16 + srow) * KD + kt * BK + kh * 32 + ss * 8;
            gload16(src, (char*)&Ak[b][kh][0] + blk * 1024);
        }
    };
    // B: per thread 2 blocks x 8 fp32 (two f32x4) per kh-region
    auto loadB = [&](f32x4* bl, const float* wP, int kt, int kh) {
        #pragma unroll
        for (int q = 0; q < 2; ++q) {
            int blk = wid * 2 + q;
            const float* src = wP + (size_t)(blk * 16 + srow) * KD + kt * BK + kh * 32 + sslot * 8;
            bl[2 * q]     = *(const f32x4*)(src);
            bl[2 * q + 1] = *(const f32x4*)(src + 4);
        }
    };
    auto writeB = [&](int b, int kh, const f32x4* bl) {
        #pragma unroll
        for (int q = 0; q < 2; ++q) {
            int blk = wid * 2 + q;
            f32x4 lo = bl[2 * q], hi = bl[2 * q + 1];
            us8 v = (us8){f2bf(lo[0]), f2bf(lo[1]), f2bf(lo[2]), f2bf(lo[3]),
                          f2bf(hi[0]), f2bf(hi[1]), f2bf(hi[2]), f2bf(hi[3])};
            *(us8*)((char*)&Bk[b][kh][0] + blk * 1024 + srow * 64 + ssw * 16) = v;
        }
    };
    auto ldA = [&](short8* a, int b, int kh) {
        #pragma unroll
        for (int mf = 0; mf < 8; ++mf) {
            int row  = wr * 128 + mf * 16 + lr;
            int slot = kg ^ ((row >> 1) & 3);
            a[mf] = *(const short8*)&Ak[b][kh][row * 32 + slot * 8];
        }
    };
    auto ldB4 = [&](short8* bf, int b, int kh) {
        #pragma unroll
        for (int i = 0; i < 4; ++i) {
            int row  = wc * 64 + i * 16 + lr;
            int slot = kg ^ ((row >> 1) & 3);
            bf[i] = *(const short8*)&Bk[b][kh][row * 32 + slot * 8];
        }
    };

    f32x4 acc[8][4];
    #pragma unroll
    for (int mf = 0; mf < 8; ++mf)
        #pragma unroll
        for (int nf = 0; nf < 4; ++nf)
            acc[mf][nf] = (f32x4){0.f, 0.f, 0.f, 0.f};

    // B in-flight register groups (ring-persistent across tiles AND slots)
    f32x4 bl0[4], bl1[4];

    // slot metadata (cur / next)
    const unsigned short *xC, *xN;
    const float *wC, *wN;
    float *oC, *oN;
    int msC, r0C, c0C, msN, r0N, c0N;
    {
        int v = s_live[0]; int e = v >> 5, br = (v >> 2) & 7, bcl = v & 3;
        r0C = br * BM; c0C = (xcd * 4 + bcl) * BN; msC = ms[e];
        xC = xb + ((size_t)e * MAXM + r0C) * KD;
        wC = w  + ((size_t)e * ND + c0C) * KD;
        oC = out + (size_t)e * MAXM * ND;
    }
    if (nlive > 1) {
        int v = s_live[1]; int e = v >> 5, br = (v >> 2) & 7, bcl = v & 3;
        r0N = br * BM; c0N = (xcd * 4 + bcl) * BN; msN = ms[e];
        xN = xb + ((size_t)e * MAXM + r0N) * KD;
        wN = w  + ((size_t)e * ND + c0N) * KD;
        oN = out + (size_t)e * MAXM * ND;
    } else { xN = xC; wN = wC; oN = oC; msN = msC; r0N = r0C; c0N = c0C; }

    // prologue: A(0,kh0),(0,kh1),(1,kh0) gloads; B(0,kh0),(0,kh1) via reg+write
    // (one-time serial cvt waits); prime bl1 = B(1,kh1) for P0(0)'s writeB.
    stageA(0, 0, xC, 0); stageA(0, 1, xC, 0); stageA(1, 0, xC, 1);
    loadB(bl0, wC, 0, 0); writeB(0, 0, bl0);
    loadB(bl0, wC, 0, 1); writeB(0, 1, bl0);
    loadB(bl1, wC, 1, 1);
    asm volatile("s_waitcnt vmcnt(4) lgkmcnt(0)" ::: "memory");
    __builtin_amdgcn_s_barrier();

    #pragma unroll 1
    for (int s = 0; s < nlive; ++s) {
        bool last  = (s + 1 >= nlive);
        bool alive = (r0C + wr * 128) < msC;   // wave-uniform dead-half skip

        #pragma unroll 1
        for (int kt = 0; kt < NTS; ++kt) {
            int b = kt & 1;
            bool g1 = (kt + 1 < NTS) || (!last);   // tile t+1 exists
            bool g2 = (kt + 2 < NTS) || (!last);   // tile t+2 exists
            const unsigned short* xS1 = (kt + 1 < NTS) ? xC : xN;
            const float*          wF1 = (kt + 1 < NTS) ? wC : wN;
            int k1 = (kt + 1 < NTS) ? kt + 1 : 0;
            const unsigned short* xS2 = (kt + 2 < NTS) ? xC : xN;
            const float*          wF2 = (kt + 2 < NTS) ? wC : wN;
            int k2 = (kt + 2 < NTS) ? kt + 2 : kt + 2 - NTS;

            short8 a[8], bf[4];

            // ======== P0: compute kh0 | stage A(t+1,kh1) | load B(t+1,kh0) |
            //          write B(t+1,kh1) from bl1 (loaded prev P1)
            if (g1) stageA(b ^ 1, 1, xS1, k1);
            if (g1) loadB(bl0, wF1, k1, 0);
            if (alive) { ldB4(bf, b, 0); ldA(a, b, 0); }
            __builtin_amdgcn_s_barrier();
            __builtin_amdgcn_s_setprio(1);
            if (alive) {
                #pragma unroll
                for (int mf = 0; mf < 8; ++mf)
                    #pragma unroll
                    for (int nf = 0; nf < 4; ++nf)
                        acc[mf][nf] = __builtin_amdgcn_mfma_f32_16x16x32_bf16(a[mf], bf[nf], acc[mf][nf], 0, 0, 0);
            }
            __builtin_amdgcn_s_setprio(0);
            if (g1) writeB(b ^ 1, 1, bl1);   // cvt-wait drains P1(t-1) loads (+older A)
            if (g1) { asm volatile("s_waitcnt vmcnt(6) lgkmcnt(0)" ::: "memory"); }
            else    { asm volatile("s_waitcnt vmcnt(0) lgkmcnt(0)" ::: "memory"); }
            __builtin_amdgcn_s_barrier();

            // ======== P1: compute kh1 | stage A(t+2,kh0) | load B(t+2,kh1) |
            //          write B(t+1,kh0) from bl0 (loaded this P0)
            if (g2) stageA(b, 0, xS2, k2);
            if (g2) loadB(bl1, wF2, k2, 1);
            if (alive) { ldB4(bf, b, 1); ldA(a, b, 1); }
            __builtin_amdgcn_s_barrier();
            __builtin_amdgcn_s_setprio(1);
            if (alive) {
                #pragma unroll
                for (int mf = 0; mf < 8; ++mf)
                    #pragma unroll
                    for (int nf = 0; nf < 4; ++nf)
                        acc[mf][nf] = __builtin_amdgcn_mfma_f32_16x16x32_bf16(a[mf], bf[nf], acc[mf][nf], 0, 0, 0);
            }
            __builtin_amdgcn_s_setprio(0);
            if (g1) writeB(b ^ 1, 0, bl0);   // cvt-wait drains P0(t) loads (+its A)
            if (g2) { asm volatile("s_waitcnt vmcnt(6) lgkmcnt(0)" ::: "memory"); }
            else    { asm volatile("s_waitcnt vmcnt(0) lgkmcnt(0)" ::: "memory"); }
            __builtin_amdgcn_s_barrier();
        }

        // epilogue for this slot (overlaps already-issued next-slot prefetch)
        #pragma unroll
        for (int mf = 0; mf < 8; ++mf) {
            int rbase = r0C + wr * 128 + mf * 16 + kg * 4;
            #pragma unroll
            for (int nf = 0; nf < 4; ++nf) {
                int gc = c0C + wc * 64 + nf * 16 + lr;
                #pragma unroll
                for (int q = 0; q < 4; ++q) {
                    int gr = rbase + q;
                    float v = (gr < msC) ? acc[mf][nf][q] : 0.f;
                    oC[(size_t)gr * ND + gc] = v;
                    acc[mf][nf][q] = 0.f;
                }
            }
        }

        // shift slot window
        xC = xN; wC = wN; oC = oN; msC = msN; r0C = r0N; c0C = c0N;
        if (s + 2 < nlive) {
            int v = s_live[s + 2]; int e = v >> 5, br = (v >> 2) & 7, bcl = v & 3;
            r0N = br * BM; c0N = (xcd * 4 + bcl) * BN; msN = ms[e];
            xN = xb + ((size_t)e * MAXM + r0N) * KD;
            wN = w  + ((size_t)e * ND + c0N) * KD;
            oN = out + (size_t)e * MAXM * ND;
        }
    }
}

// ---------------- Fallback: round-1 fused kernel (used only if ws too small) --------
#define FBM 128
#define FBK 32
#define FTM (MAXM/FBM)
#define FTN (ND/FBM)
#define FNT (KD/FBK)
#define LSTR 40
__global__ __launch_bounds__(256, 2) void ggemm_fused(
    const float* __restrict__ x, const float* __restrict__ w,
    const int* __restrict__ ms, float* __restrict__ out)
{
    int nwg  = gridDim.x;
    int orig = blockIdx.x;
    int cpx  = nwg >> 3;
    int bid  = (orig & 7) * cpx + (orig >> 3);
    int e   = bid / (FTM * FTN);
    int rem = bid % (FTM * FTN);
    int br  = rem % FTM;
    int bc  = rem / FTM;
    int m_size = ms[e];
    int row0 = br * FBM, col0 = bc * FBM;
    float* outE = out + (size_t)e * MAXM * ND;
    int tid = threadIdx.x;

    if (row0 >= m_size) {
        f32x4 z = (f32x4){0.f, 0.f, 0.f, 0.f};
        #pragma unroll
        for (int q = 0; q < 16; ++q) {
            int i2 = tid + q * 256;
            int rr = i2 >> 5, cc = (i2 & 31) << 2;
            *(f32x4*)(outE + (size_t)(row0 + rr) * ND + col0 + cc) = z;
        }
        return;
    }

    const float* xE = x + ((size_t)e * MAXM + row0) * KD;
    const float* wE = w + ((size_t)e * ND   + col0) * KD;

    __shared__ unsigned short As[2][FBM][LSTR];
    __shared__ unsigned short Bs[2][FBM][LSTR];

    int sr  = tid >> 3;
    int sc4 = tid & 7;
    int wid = tid >> 6, lane = tid & 63;
    int wr = wid >> 1, wc = wid & 1;
    int lr = lane & 15, kg = lane >> 4;

    f32x4 acc[4][4];
    #pragma unroll
    for (int m = 0; m < 4; ++m)
        #pragma unroll
        for (int n = 0; n < 4; ++n)
            acc[m][n] = (f32x4){0.f, 0.f, 0.f, 0.f};

    {
        #pragma unroll
        for (int q = 0; q < 4; ++q) {
            int r0 = sr + q * 32;
            f32x4 av = *(const f32x4*)(xE + (size_t)r0 * KD + sc4 * 4);
            f32x4 bv = *(const f32x4*)(wE + (size_t)r0 * KD + sc4 * 4);
            us4 ah = (us4){f2bf(av[0]), f2bf(av[1]), f2bf(av[2]), f2bf(av[3])};
            us4 bh = (us4){f2bf(bv[0]), f2bf(bv[1]), f2bf(bv[2]), f2bf(bv[3])};
            *(us4*)&As[0][r0][sc4 * 4] = ah;
            *(us4*)&Bs[0][r0][sc4 * 4] = bh;
        }
    }
    __syncthreads();

    for (int t = 0; t < FNT; ++t) {
        int cur = t & 1;
        f32x4 av[4], bv[4];
        bool pre = (t + 1 < FNT);
        if (pre) {
            const float* xk = xE + (size_t)(t + 1) * FBK;
            const float* wk = wE + (size_t)(t + 1) * FBK;
            #pragma unroll
            for (int q = 0; q < 4; ++q) {
                int r0 = sr + q * 32;
                av[q] = *(const f32x4*)(xk + (size_t)r0 * KD + sc4 * 4);
                bv[q] = *(const f32x4*)(wk + (size_t)r0 * KD + sc4 * 4);
            }
        }
        short8 a[4], b[4];
        #pragma unroll
        for (int m = 0; m < 4; ++m)
            a[m] = *(const short8*)&As[cur][wr * 64 + m * 16 + lr][kg * 8];
        #pragma unroll
        for (int n = 0; n < 4; ++n)
            b[n] = *(const short8*)&Bs[cur][wc * 64 + n * 16 + lr][kg * 8];
        #pragma unroll
        for (int m = 0; m < 4; ++m)
            #pragma unroll
            for (int n = 0; n < 4; ++n)
                acc[m][n] = __builtin_amdgcn_mfma_f32_16x16x32_bf16(a[m], b[n], acc[m][n], 0, 0, 0);

        if (pre) {
            int nb = cur ^ 1;
            #pragma unroll
            for (int q = 0; q < 4; ++q) {
                int r0 = sr + q * 32;
                us4 ah = (us4){f2bf(av[q][0]), f2bf(av[q][1]), f2bf(av[q][2]), f2bf(av[q][3])};
                us4 bh = (us4){f2bf(bv[q][0]), f2bf(bv[q][1]), f2bf(bv[q][2]), f2bf(bv[q][3])};
                *(us4*)&As[nb][r0][sc4 * 4] = ah;
                *(us4*)&Bs[nb][r0][sc4 * 4] = bh;
            }
        }
        __syncthreads();
    }

    #pragma unroll
    for (int m = 0; m < 4; ++m) {
        int rbase = row0 + wr * 64 + m * 16 + kg * 4;
        #pragma unroll
        for (int n = 0; n < 4; ++n) {
            int gc = col0 + wc * 64 + n * 16 + lr;
            #pragma unroll
            for (int q = 0; q < 4; ++q) {
                int gr = rbase + q;
                float v = (gr < m_size) ? acc[m][n][q] : 0.f;
                outE[(size_t)gr * ND + gc] = v;
            }
        }
    }
}

extern "C" void kernel_launch(void* const* d_in, const int* in_sizes, int n_in,
                              void* d_out, int out_size, void* d_ws, size_t ws_size,
                              hipStream_t stream) {
    const float* x  = (const float*)d_in[0];
    const float* w  = (const float*)d_in[1];
    const int*   ms = (const int*)d_in[2];
    float* out = (float*)d_out;

    const size_t xElems = (size_t)NE * MAXM * KD;   // 33,554,432
    const size_t need   = xElems * 2;               // 67 MB (X bf16 only)

    if (ws_size >= need) {
        unsigned short* xb = (unsigned short*)d_ws;
        cvt_x_kernel<<<NE * MAXM, 256, 0, stream>>>(x, xb, ms);
        ggemm_pers<<<256, 512, 0, stream>>>(xb, w, ms, out);
    } else {
        ggemm_fused<<<dim3(NE * (MAXM/FBM) * (ND/FBM)), dim3(256), 0, stream>>>(x, w, ms, out);
    }
}